// Round 3
// baseline (490.158 us; speedup 1.0000x reference)
//
#include <hip/hip_runtime.h>
#include <hip/hip_bf16.h>
#include <stdint.h>

typedef _Float16 f16;
typedef _Float16 f16x4v __attribute__((ext_vector_type(4)));
typedef _Float16 f16x8 __attribute__((ext_vector_type(8)));
typedef float f32x4 __attribute__((ext_vector_type(4)));
typedef float f32x16 __attribute__((ext_vector_type(16)));

#define B_    32
#define T_    1024
#define TP_   1026
#define C_    512
#define LMAX_ 4096
#define KDIM  1536

// workspace byte offsets (all 256-aligned)
#define XPAD_OFF   0u
#define H1PAD_OFF  33619968u     // 32*1026*512*2
#define W1T_OFF    67239936u
#define W2T_OFF    68812800u
#define TOT_OFF    70385664u
#define IDX_OFF    70385920u

#define AS1C(p) ((const __attribute__((address_space(1))) void*)(p))
#define AS3(p)  ((__attribute__((address_space(3))) void*)(p))

// ---------------------------------------------------------------------------
// prep: xpad = fp16(batch) with zero guard rows at t=-1 and t=T; also zero
// h1pad guard rows (ws is re-poisoned before every launch).
__global__ __launch_bounds__(256) void prep_pad(const float* __restrict__ batch,
                                                f16* __restrict__ xpad,
                                                f16* __restrict__ h1pad) {
    int row = blockIdx.x * 4 + (threadIdx.x >> 6);   // 0 .. B_*TP_-1
    int lane = threadIdx.x & 63;
    int b = row / TP_, tt = row % TP_;
    size_t dsto = (size_t)row * C_ + lane * 8;
    if (tt == 0 || tt == TP_ - 1) {
        f16x8 z = {};
        *(f16x8*)(xpad + dsto) = z;
        *(f16x8*)(h1pad + dsto) = z;
    } else {
        const float* src = batch + ((size_t)(b * T_ + tt - 1)) * C_ + lane * 8;
        float4 v0 = ((const float4*)src)[0];
        float4 v1 = ((const float4*)src)[1];
        f16x8 h;
        h[0] = (f16)v0.x; h[1] = (f16)v0.y; h[2] = (f16)v0.z; h[3] = (f16)v0.w;
        h[4] = (f16)v1.x; h[5] = (f16)v1.y; h[6] = (f16)v1.z; h[7] = (f16)v1.w;
        *(f16x8*)(xpad + dsto) = h;
    }
}

// ---------------------------------------------------------------------------
// prep weights: wt[o][tap*512+i] = w[o][i][tap], fp16.  w is [512][512][3].
__global__ __launch_bounds__(256) void prep_w(const float* __restrict__ w1,
                                              const float* __restrict__ w2,
                                              f16* __restrict__ w1t,
                                              f16* __restrict__ w2t) {
    int o = blockIdx.x;
    const float* w = blockIdx.y ? w2 : w1;
    f16* wt = blockIdx.y ? w2t : w1t;
    for (int j = threadIdx.x; j < KDIM; j += 256) {
        int tap = j >> 9, i = j & 511;
        wt[(size_t)o * KDIM + j] = (f16)w[(size_t)o * KDIM + i * 3 + tap];
    }
}

// ---------------------------------------------------------------------------
// per-batch duration scan + direct inverse-map scatter (searchsorted inverse).
__global__ __launch_bounds__(1024) void scan_kernel(const int* __restrict__ dur,
                                                    const int* __restrict__ tlen,
                                                    int* __restrict__ idxarr,
                                                    int* __restrict__ total,
                                                    float* __restrict__ mel_out) {
    int b = blockIdx.x, t = threadIdx.x;
    __shared__ int sd[1024];
    __shared__ int sv[1024];
    int L = tlen[b];
    int valid = (t < L) ? 1 : 0;
    int d = valid ? dur[b * T_ + t] : 0;
    sd[t] = d; sv[t] = valid;
    __syncthreads();
    for (int off = 1; off < 1024; off <<= 1) {
        int x = 0, y = 0;
        if (t >= off) { x = sd[t - off]; y = sv[t - off]; }
        __syncthreads();
        sd[t] += x; sv[t] += y;
        __syncthreads();
    }
    int totd = sd[1023];
    int cur  = (totd == 0) ? sv[t] : sd[t];
    int prev = (t == 0) ? 0 : ((totd == 0) ? sv[t - 1] : sd[t - 1]);
    for (int f = prev; f < cur; f++) idxarr[b * LMAX_ + f] = t;
    if (t == 1023) {
        int tt = (totd == 0) ? sv[1023] : totd;
        total[b] = tt;
        mel_out[b] = (float)tt;
    }
}

// ---------------------------------------------------------------------------
// Fused implicit-GEMM conv + bias + relu + LayerNorm (+ optional Linear head).
// Block = 64 rows x full N=512, 4 waves; wave w owns cols [w*128, w*128+128).
// MODE 1: write LN output as fp16 into h1pad (guard-offset rows).
// MODE 2: LN + dot(lin_w) + mask -> pred[m] only.
// Staging: global_load_lds width=16, XOR granule swizzle LDS[r][s]=glob s^(r&7).
template <int MODE>
__global__ __launch_bounds__(256, 2) void fgemm(const f16* __restrict__ A,
                                                const f16* __restrict__ Bw,
                                                const float* __restrict__ bias,
                                                const float* __restrict__ g,
                                                const float* __restrict__ be,
                                                const float* __restrict__ lw,
                                                const float* __restrict__ lb,
                                                const int* __restrict__ tlen,
                                                f16* __restrict__ hpad,
                                                float* __restrict__ pred) {
    __shared__ __align__(16) char smem[73728];
    f16* As = (f16*)smem;                 // [64][64]  (8 KB)
    f16* Bs = (f16*)(smem + 8192);        // [512][64] (64 KB)
    float* Ew = (float*)smem;             // [32][512] epilogue reuse (64 KB)

    const int tid = threadIdx.x;
    const int lane = tid & 63;
    const int w = tid >> 6;
    const int m0 = blockIdx.x * 64;
    const int arow0 = (m0 >> 10) * TP_ + (m0 & 1023);

    f32x16 acc[2][4];
#pragma unroll
    for (int i = 0; i < 2; i++)
#pragma unroll
        for (int j = 0; j < 4; j++) acc[i][j] = (f32x16){};

    const int srow = lane >> 3;                    // 0..7
    const int gran = (lane & 7) ^ srow;            // swizzled source granule
    const f16* aB = A + (size_t)(arow0 + w * 16 + srow) * C_ + gran * 8;
    const f16* bB = Bw + (size_t)(w * 128 + srow) * KDIM + gran * 8;

    for (int kk = 0; kk < KDIM; kk += 64) {
        __syncthreads();
#pragma unroll
        for (int i = 0; i < 2; i++)
            __builtin_amdgcn_global_load_lds(AS1C(aB + (size_t)(i * 8) * C_ + kk),
                                             AS3(&As[(w * 16 + i * 8) * 64]), 16, 0, 0);
#pragma unroll
        for (int j = 0; j < 16; j++)
            __builtin_amdgcn_global_load_lds(AS1C(bB + (size_t)(j * 8) * KDIM + kk),
                                             AS3(&Bs[(w * 128 + j * 8) * 64]), 16, 0, 0);
        __syncthreads();
#pragma unroll
        for (int ks = 0; ks < 4; ks++) {
            const int slot = (ks * 2 + (lane >> 5)) ^ (lane & 7);
            f16x8 af[2], bf[4];
#pragma unroll
            for (int mt = 0; mt < 2; mt++)
                af[mt] = *(const f16x8*)&As[(mt * 32 + (lane & 31)) * 64 + slot * 8];
#pragma unroll
            for (int nt = 0; nt < 4; nt++)
                bf[nt] = *(const f16x8*)&Bs[(w * 128 + nt * 32 + (lane & 31)) * 64 + slot * 8];
#pragma unroll
            for (int mt = 0; mt < 2; mt++)
#pragma unroll
                for (int nt = 0; nt < 4; nt++)
                    acc[mt][nt] = __builtin_amdgcn_mfma_f32_32x32x16_f16(
                        af[mt], bf[nt], acc[mt][nt], 0, 0, 0);
        }
    }

    // ---- fused epilogue: bias+relu -> LDS (fp32) -> per-row LN ----
    float bcol[4];
#pragma unroll
    for (int nt = 0; nt < 4; nt++) bcol[nt] = bias[w * 128 + nt * 32 + (lane & 31)];
    const float4 gA = ((const float4*)g)[lane], gB = ((const float4*)g)[64 + lane];
    const float4 eA = ((const float4*)be)[lane], eB = ((const float4*)be)[64 + lane];
    float4 wA, wB;
    if (MODE == 2) { wA = ((const float4*)lw)[lane]; wB = ((const float4*)lw)[64 + lane]; }

#pragma unroll
    for (int c = 0; c < 2; c++) {
        __syncthreads();      // chunk LDS free (frag reads done / prev readers done)
#pragma unroll
        for (int nt = 0; nt < 4; nt++) {
            const int col = w * 128 + nt * 32 + (lane & 31);
#pragma unroll
            for (int reg = 0; reg < 16; reg++) {
                const int row = (reg & 3) + 8 * (reg >> 2) + 4 * (lane >> 5);
                float v = acc[c][nt][reg] + bcol[nt];
                Ew[row * 512 + col] = v > 0.f ? v : 0.f;
            }
        }
        __syncthreads();
#pragma unroll
        for (int i = 0; i < 8; i++) {
            const int r = w + i * 4;                    // rows 0..31 across 4 waves
            float4 v0 = *(const float4*)&Ew[r * 512 + lane * 4];
            float4 v1 = *(const float4*)&Ew[r * 512 + 256 + lane * 4];
            float s = v0.x + v0.y + v0.z + v0.w + v1.x + v1.y + v1.z + v1.w;
            float q = v0.x * v0.x + v0.y * v0.y + v0.z * v0.z + v0.w * v0.w +
                      v1.x * v1.x + v1.y * v1.y + v1.z * v1.z + v1.w * v1.w;
#pragma unroll
            for (int m = 32; m; m >>= 1) { s += __shfl_xor(s, m, 64); q += __shfl_xor(q, m, 64); }
            float mu = s * (1.f / 512.f);
            float x = q * (1.f / 512.f) - mu * mu + 1e-5f;
            float rs = rsqrtf(x);
            rs = rs * (1.5f - 0.5f * x * rs * rs);      // Newton refine
            const int m = m0 + c * 32 + r;
            const int b = m >> 10, t = m & 1023;
            if (MODE == 1) {
                f16x4v h0, h1;
                h0[0] = (f16)((v0.x - mu) * rs * gA.x + eA.x);
                h0[1] = (f16)((v0.y - mu) * rs * gA.y + eA.y);
                h0[2] = (f16)((v0.z - mu) * rs * gA.z + eA.z);
                h0[3] = (f16)((v0.w - mu) * rs * gA.w + eA.w);
                h1[0] = (f16)((v1.x - mu) * rs * gB.x + eB.x);
                h1[1] = (f16)((v1.y - mu) * rs * gB.y + eB.y);
                h1[2] = (f16)((v1.z - mu) * rs * gB.z + eB.z);
                h1[3] = (f16)((v1.w - mu) * rs * gB.w + eB.w);
                f16* dst = hpad + ((size_t)(b * TP_ + t + 1)) * C_;
                *(f16x4v*)(dst + lane * 4) = h0;
                *(f16x4v*)(dst + 256 + lane * 4) = h1;
            } else {
                float p = ((v0.x - mu) * rs * gA.x + eA.x) * wA.x +
                          ((v0.y - mu) * rs * gA.y + eA.y) * wA.y +
                          ((v0.z - mu) * rs * gA.z + eA.z) * wA.z +
                          ((v0.w - mu) * rs * gA.w + eA.w) * wA.w +
                          ((v1.x - mu) * rs * gB.x + eB.x) * wB.x +
                          ((v1.y - mu) * rs * gB.y + eB.y) * wB.y +
                          ((v1.z - mu) * rs * gB.z + eB.z) * wB.z +
                          ((v1.w - mu) * rs * gB.w + eB.w) * wB.w;
#pragma unroll
                for (int mm = 32; mm; mm >>= 1) p += __shfl_xor(p, mm, 64);
                if (lane == 0) pred[m] = (t < tlen[b]) ? (p + lb[0]) : 0.f;
            }
        }
    }
}

// ---------------------------------------------------------------------------
// regulate gather: wave per output frame row; precomputed idx (no search).
__global__ __launch_bounds__(256) void gather_kernel(const float* __restrict__ batch,
                                                     const int* __restrict__ idxarr,
                                                     const int* __restrict__ total,
                                                     float* __restrict__ out) {
    int gw = blockIdx.x * 4 + (threadIdx.x >> 6);  // 0 .. B_*LMAX_-1
    int lane = threadIdx.x & 63;
    int b = gw >> 12;
    int l = gw & (LMAX_ - 1);
    int tot = total[b];
    float4* dst = (float4*)(out + ((size_t)b * LMAX_ + l) * C_);
    if (l < tot) {
        int idx = idxarr[gw];
        const float4* src = (const float4*)(batch + ((size_t)b * T_ + idx) * C_);
        dst[lane] = src[lane];
        dst[lane + 64] = src[lane + 64];
    } else {
        float4 z = {0.f, 0.f, 0.f, 0.f};
        dst[lane] = z;
        dst[lane + 64] = z;
    }
}

// ---------------------------------------------------------------------------
extern "C" void kernel_launch(void* const* d_in, const int* in_sizes, int n_in,
                              void* d_out, int out_size, void* d_ws, size_t ws_size,
                              hipStream_t stream) {
    const float* batch = (const float*)d_in[0];
    const int* tlen    = (const int*)d_in[1];
    // d_in[2] = mask, recomputed from token_lengths instead
    const int* durs    = (const int*)d_in[3];
    const float* w1  = (const float*)d_in[4];
    const float* b1  = (const float*)d_in[5];
    const float* g1  = (const float*)d_in[6];
    const float* be1 = (const float*)d_in[7];
    const float* w2  = (const float*)d_in[8];
    const float* b2  = (const float*)d_in[9];
    const float* g2  = (const float*)d_in[10];
    const float* be2 = (const float*)d_in[11];
    const float* lw  = (const float*)d_in[12];
    const float* lb  = (const float*)d_in[13];

    float* out      = (float*)d_out;
    float* mel_out  = out + (size_t)B_ * LMAX_ * C_;
    float* pred_out = mel_out + B_;

    char* ws    = (char*)d_ws;
    f16* xpad   = (f16*)(ws + XPAD_OFF);
    f16* h1pad  = (f16*)(ws + H1PAD_OFF);
    f16* w1t    = (f16*)(ws + W1T_OFF);
    f16* w2t    = (f16*)(ws + W2T_OFF);
    int* tot    = (int*)(ws + TOT_OFF);
    int* idxarr = (int*)(ws + IDX_OFF);

    prep_pad<<<B_ * TP_ / 4, 256, 0, stream>>>(batch, xpad, h1pad);
    prep_w<<<dim3(512, 2), 256, 0, stream>>>(w1, w2, w1t, w2t);
    scan_kernel<<<B_, 1024, 0, stream>>>(durs, tlen, idxarr, tot, mel_out);
    fgemm<1><<<512, 256, 0, stream>>>(xpad, w1t, b1, g1, be1, nullptr, nullptr, nullptr,
                                      h1pad, nullptr);
    fgemm<2><<<512, 256, 0, stream>>>(h1pad, w2t, b2, g2, be2, lw, lb, tlen,
                                      nullptr, pred_out);
    gather_kernel<<<B_ * LMAX_ / 4, 256, 0, stream>>>(batch, idxarr, tot, out);
}